// Round 2
// 11997.283 us; speedup vs baseline: 2.0838x; 2.0838x over previous
//
#include <hip/hip_runtime.h>
#include <cstdint>

// B=32, S=64, T=64, D=256, H=512, 3H=1536, VOUT=32000
// Round 5: round-4 (coalesced K-major weight layout for step kernels) with the
// DOT4 macro-hygiene compile bug fixed (macro param 'w' captured member '.w';
// now an inline function).

__device__ __forceinline__ float sigm(float x) { return 1.f / (1.f + __expf(-x)); }
__device__ __forceinline__ float dot4(float4 a, float4 b) {
    return a.x * b.x + a.y * b.y + a.z * b.z + a.w * b.w;
}

// ---------------- init ----------------
__global__ void k_zero2(float* a, float* b) {
    int i = blockIdx.x * 256 + threadIdx.x;
    a[i] = 0.f; b[i] = 0.f;
}

// ---------------- embedding gathers ----------------
__global__ void k_gather_enc(const int* __restrict__ seq, const float* __restrict__ E,
                             float* __restrict__ out) {
    int r = blockIdx.x;            // s*32+b
    int s = r >> 5, b = r & 31;
    int tok = seq[b * 64 + s];
    float4 v = ((const float4*)(E + (size_t)tok * 256))[threadIdx.x];
    ((float4*)(out + (size_t)r * 256))[threadIdx.x] = v;
}
__global__ void k_gather_dec(const int* __restrict__ tgt, const float* __restrict__ E,
                             float* __restrict__ out) {
    int r = blockIdx.x;            // t*32+b
    int t = r >> 5, b = r & 31;
    int tok = (t == 0) ? 0 : tgt[b * 64 + (t - 1)];
    float4 v = ((const float4*)(E + (size_t)tok * 256))[threadIdx.x];
    ((float4*)(out + (size_t)r * 256))[threadIdx.x] = v;
}

// ---------------- pack-transpose ----------------
// out4[(k>>2)*W + c][j] = in[c*ldin + coloff + k], j = k&3.  K fixed at 512.
// grid (16, W/32), block 256.
__global__ __launch_bounds__(256) void k_transpose4(
    const float* __restrict__ in, float* __restrict__ out,
    int W, int ldin, int coloff)
{
    __shared__ float t[32][33];
    int k0 = blockIdx.x * 32, c0 = blockIdx.y * 32;
    int tx = threadIdx.x & 31, ty = threadIdx.x >> 5;
    #pragma unroll
    for (int i = 0; i < 32; i += 8)
        t[ty + i][tx] = in[(size_t)(c0 + ty + i) * ldin + coloff + k0 + tx];
    __syncthreads();
    float4 v;
    v.x = t[tx][4 * ty + 0];
    v.y = t[tx][4 * ty + 1];
    v.z = t[tx][4 * ty + 2];
    v.w = t[tx][4 * ty + 3];
    ((float4*)out)[(size_t)((k0 >> 2) + ty) * W + c0 + tx] = v;
}

// ---------------- simple tiled fp32 GEMM (unchanged, known-good) ----------------
__global__ __launch_bounds__(256) void k_sgemm(
    const float* __restrict__ A, int lda,
    const float* __restrict__ W, int ldw, int coloff,
    const float* __restrict__ bias,
    float* __restrict__ outF, int N, int K, int out_mode)
{
    __shared__ float As[16][68];
    __shared__ float Ws[16][68];
    int tid = threadIdx.x;
    int tx = tid & 15, ty = tid >> 4;
    int m_base = blockIdx.y * 64;
    int n_base = blockIdx.x * 64;
    float acc[4][4] = {};

    for (int k0 = 0; k0 < K; k0 += 16) {
        #pragma unroll
        for (int i = 0; i < 4; i++) {
            int e = tid + 256 * i;
            int mm = e >> 4, kk = e & 15;
            As[kk][mm] = A[(size_t)(m_base + mm) * lda + k0 + kk];
            Ws[kk][mm] = W[(size_t)(n_base + mm) * ldw + coloff + k0 + kk];
        }
        __syncthreads();
        #pragma unroll
        for (int kk = 0; kk < 16; kk++) {
            float4 av = *(const float4*)&As[kk][ty * 4];
            float4 wv = *(const float4*)&Ws[kk][tx * 4];
            float a[4] = {av.x, av.y, av.z, av.w};
            float w[4] = {wv.x, wv.y, wv.z, wv.w};
            #pragma unroll
            for (int i = 0; i < 4; i++)
                #pragma unroll
                for (int j = 0; j < 4; j++)
                    acc[i][j] += a[i] * w[j];
        }
        __syncthreads();
    }

    #pragma unroll
    for (int j = 0; j < 4; j++) {
        int n = n_base + tx * 4 + j;
        float bv = bias ? bias[n] : 0.f;
        #pragma unroll
        for (int i = 0; i < 4; i++) {
            int m = m_base + ty * 4 + i;
            float v = acc[i][j] + bv;
            if (out_mode == 0) {
                outF[(size_t)m * N + n] = v;
            } else {
                int t = m >> 5, b = m & 31;
                outF[((size_t)(b * 64 + t)) * N + n] = v;
            }
        }
    }
}

// ---------------- encoder GRU step (coalesced) ----------------
// grid (16, 4), block 256. i = bx*32+(tid&31) in [0,512), b = by*8+(tid>>5).
__global__ __launch_bounds__(256) void k_gru_step(
    const float* __restrict__ gi,     // [32][1536] this step (bx included)
    const float* __restrict__ WhT4,   // packed [128][1536][4]
    const float* __restrict__ bh,
    const float* __restrict__ hin, float* __restrict__ hout,
    float* __restrict__ yout, int ystride)
{
    __shared__ __align__(16) float hs[8][512];
    int tid = threadIdx.x;
    int il = tid & 31, bl = tid >> 5;
    int i = blockIdx.x * 32 + il;
    int b = blockIdx.y * 8 + bl;
    for (int e = tid; e < 4096; e += 256) {
        int bb = e >> 9, k = e & 511;
        hs[bb][k] = hin[(blockIdx.y * 8 + bb) * 512 + k];
    }
    __syncthreads();
    const float* hp = hs[bl];
    const float4* W4 = (const float4*)WhT4;
    float a0 = 0.f, a1 = 0.f, a2 = 0.f;
    #pragma unroll 4
    for (int k4 = 0; k4 < 128; k4++) {
        float4 h4 = *(const float4*)&hp[4 * k4];
        size_t base = (size_t)k4 * 1536 + i;
        float4 w0 = W4[base];
        float4 w1 = W4[base + 512];
        float4 w2 = W4[base + 1024];
        a0 += dot4(w0, h4); a1 += dot4(w1, h4); a2 += dot4(w2, h4);
    }
    const float* gir = gi + b * 1536;
    float gr  = gir[i]        + a0 + bh[i];
    float gz  = gir[i + 512]  + a1 + bh[i + 512];
    float gin = gir[i + 1024];
    float ghn = a2 + bh[i + 1024];
    float r = sigm(gr), z = sigm(gz);
    float n = tanhf(gin + r * ghn);
    float hnew = (1.f - z) * n + z * hp[i];
    hout[b * 512 + i] = hnew;
    yout[(size_t)b * ystride + i] = hnew;
}

// ---------------- decoder GRU layer 0 step (coalesced) ----------------
__global__ __launch_bounds__(256) void k_gru_d0(
    const float* __restrict__ pregi,  // [32][1536] (emb part + bx)
    const float* __restrict__ WhT4,   // [128][1536][4]
    const float* __restrict__ WcT4,   // [128][1536][4] (ctx cols of Wx_d0)
    const float* __restrict__ bh,
    const float* __restrict__ ctx,
    const float* __restrict__ hin, float* __restrict__ hout)
{
    __shared__ __align__(16) float hs[8][512];
    __shared__ __align__(16) float cs[8][512];
    int tid = threadIdx.x;
    int il = tid & 31, bl = tid >> 5;
    int i = blockIdx.x * 32 + il;
    int b = blockIdx.y * 8 + bl;
    for (int e = tid; e < 4096; e += 256) {
        int bb = e >> 9, k = e & 511;
        int g = (blockIdx.y * 8 + bb) * 512 + k;
        hs[bb][k] = hin[g];
        cs[bb][k] = ctx[g];
    }
    __syncthreads();
    const float* hp = hs[bl];
    const float* cp = cs[bl];
    const float4* Wh4 = (const float4*)WhT4;
    const float4* Wc4 = (const float4*)WcT4;
    float a0 = 0.f, a1 = 0.f, a2 = 0.f, c0 = 0.f, c1 = 0.f, c2 = 0.f;
    #pragma unroll 2
    for (int k4 = 0; k4 < 128; k4++) {
        float4 h4 = *(const float4*)&hp[4 * k4];
        float4 c4 = *(const float4*)&cp[4 * k4];
        size_t base = (size_t)k4 * 1536 + i;
        float4 p0 = Wh4[base], p1 = Wh4[base + 512], p2 = Wh4[base + 1024];
        float4 q0 = Wc4[base], q1 = Wc4[base + 512], q2 = Wc4[base + 1024];
        a0 += dot4(p0, h4); a1 += dot4(p1, h4); a2 += dot4(p2, h4);
        c0 += dot4(q0, c4); c1 += dot4(q1, c4); c2 += dot4(q2, c4);
    }
    const float* gir = pregi + b * 1536;
    float gr  = gir[i]        + c0 + a0 + bh[i];
    float gz  = gir[i + 512]  + c1 + a1 + bh[i + 512];
    float gin = gir[i + 1024] + c2;
    float ghn = a2 + bh[i + 1024];
    float r = sigm(gr), z = sigm(gz);
    float n = tanhf(gin + r * ghn);
    hout[b * 512 + i] = (1.f - z) * n + z * hp[i];
}

// ---------------- decoder GRU layer 1 step (coalesced) ----------------
__global__ __launch_bounds__(256) void k_gru_d1(
    const float* __restrict__ WxT4, const float* __restrict__ bx,
    const float* __restrict__ WhT4, const float* __restrict__ bh,
    const float* __restrict__ x,     // new h0
    const float* __restrict__ hin, float* __restrict__ hout,
    float* __restrict__ H1step)
{
    __shared__ __align__(16) float xs[8][512];
    __shared__ __align__(16) float hs[8][512];
    int tid = threadIdx.x;
    int il = tid & 31, bl = tid >> 5;
    int i = blockIdx.x * 32 + il;
    int b = blockIdx.y * 8 + bl;
    for (int e = tid; e < 4096; e += 256) {
        int bb = e >> 9, k = e & 511;
        int g = (blockIdx.y * 8 + bb) * 512 + k;
        xs[bb][k] = x[g];
        hs[bb][k] = hin[g];
    }
    __syncthreads();
    const float* xp = xs[bl];
    const float* hp = hs[bl];
    const float4* Wx4 = (const float4*)WxT4;
    const float4* Wh4 = (const float4*)WhT4;
    float g0 = 0.f, g1 = 0.f, g2 = 0.f, a0 = 0.f, a1 = 0.f, a2 = 0.f;
    #pragma unroll 2
    for (int k4 = 0; k4 < 128; k4++) {
        float4 x4 = *(const float4*)&xp[4 * k4];
        float4 h4 = *(const float4*)&hp[4 * k4];
        size_t base = (size_t)k4 * 1536 + i;
        float4 p0 = Wx4[base], p1 = Wx4[base + 512], p2 = Wx4[base + 1024];
        float4 q0 = Wh4[base], q1 = Wh4[base + 512], q2 = Wh4[base + 1024];
        g0 += dot4(p0, x4); g1 += dot4(p1, x4); g2 += dot4(p2, x4);
        a0 += dot4(q0, h4); a1 += dot4(q1, h4); a2 += dot4(q2, h4);
    }
    float gr  = g0 + bx[i]        + a0 + bh[i];
    float gz  = g1 + bx[i + 512]  + a1 + bh[i + 512];
    float gin = g2 + bx[i + 1024];
    float ghn = a2 + bh[i + 1024];
    float r = sigm(gr), z = sigm(gz);
    float n = tanhf(gin + r * ghn);
    float hnew = (1.f - z) * n + z * hp[i];
    hout[b * 512 + i] = hnew;
    H1step[(size_t)b * 512 + i] = hnew;
}

// ---------------- attention ph = h1 @ Wattn[:, :512]^T (coalesced) ----------------
// grid (16, 4): j = bx*32+(tid&31), b = by*8+(tid>>5)
__global__ __launch_bounds__(256) void k_attn_ph(
    const float* __restrict__ h1, const float* __restrict__ WaT4, // [128][512][4]
    float* __restrict__ ph)
{
    __shared__ __align__(16) float hs[8][512];
    int tid = threadIdx.x;
    int il = tid & 31, bl = tid >> 5;
    int j = blockIdx.x * 32 + il;
    int b = blockIdx.y * 8 + bl;
    for (int e = tid; e < 4096; e += 256) {
        int bb = e >> 9, k = e & 511;
        hs[bb][k] = h1[(blockIdx.y * 8 + bb) * 512 + k];
    }
    __syncthreads();
    const float* hp = hs[bl];
    const float4* W4 = (const float4*)WaT4;
    float a = 0.f;
    #pragma unroll 4
    for (int k4 = 0; k4 < 128; k4++) {
        float4 h4 = *(const float4*)&hp[4 * k4];
        float4 w = W4[(size_t)k4 * 512 + j];
        a += dot4(w, h4);
    }
    ph[b * 512 + j] = a;
}

// ---------------- attention scores/softmax/ctx (per-b block) ----------------
__global__ __launch_bounds__(256) void k_attn_sc(
    const float* __restrict__ ph,     // [32][512]
    const float* __restrict__ preenc, // [32*64,512] row b*64+s (b_attn included)
    const float* __restrict__ enc,    // [32*64,512] row b*64+s
    const float* __restrict__ vattn,
    float* __restrict__ ctx)
{
    __shared__ float phs[512], red[256], sc[64], aw[64];
    int b = blockIdx.x, tid = threadIdx.x;
    phs[tid]       = ph[b * 512 + tid];
    phs[tid + 256] = ph[b * 512 + tid + 256];
    __syncthreads();

    int s = tid >> 2, q = tid & 3;
    const float* pe = preenc + ((size_t)b * 64 + s) * 512;
    float part = 0.f;
    for (int h = q; h < 512; h += 4)
        part += vattn[h] * tanhf(pe[h] + phs[h]);
    red[tid] = part;
    __syncthreads();
    if (q == 0) sc[s] = red[tid] + red[tid + 1] + red[tid + 2] + red[tid + 3];
    __syncthreads();
    if (tid == 0) {
        float mx = -1e30f;
        for (int k = 0; k < 64; k++) mx = fmaxf(mx, sc[k]);
        float sum = 0.f;
        for (int k = 0; k < 64; k++) { float e = __expf(sc[k] - mx); aw[k] = e; sum += e; }
        float inv = 1.f / sum;
        for (int k = 0; k < 64; k++) aw[k] *= inv;
    }
    __syncthreads();

    #pragma unroll
    for (int jj = 0; jj < 2; jj++) {
        int j = tid + jj * 256;
        float c = 0.f;
        for (int s2 = 0; s2 < 64; s2++)
            c += aw[s2] * enc[((size_t)b * 64 + s2) * 512 + j];
        ctx[b * 512 + j] = c;
    }
}

// ---------------- host ----------------
extern "C" void kernel_launch(void* const* d_in, const int* in_sizes, int n_in,
                              void* d_out, int out_size, void* d_ws, size_t ws_size,
                              hipStream_t stream)
{
    const int*   seq    = (const int*)d_in[0];
    const int*   tgt    = (const int*)d_in[1];
    const float* E_enc  = (const float*)d_in[2];
    const float* Wx_e0  = (const float*)d_in[3];
    const float* Wh_e0  = (const float*)d_in[4];
    const float* bx_e0  = (const float*)d_in[5];
    const float* bh_e0  = (const float*)d_in[6];
    const float* Wx_e1  = (const float*)d_in[7];
    const float* Wh_e1  = (const float*)d_in[8];
    const float* bx_e1  = (const float*)d_in[9];
    const float* bh_e1  = (const float*)d_in[10];
    const float* E_dec  = (const float*)d_in[11];
    const float* W_attn = (const float*)d_in[12];
    const float* b_attn = (const float*)d_in[13];
    const float* v_attn = (const float*)d_in[14];
    const float* Wx_d0  = (const float*)d_in[15];
    const float* Wh_d0  = (const float*)d_in[16];
    const float* bx_d0  = (const float*)d_in[17];
    const float* bh_d0  = (const float*)d_in[18];
    const float* Wx_d1  = (const float*)d_in[19];
    const float* Wh_d1  = (const float*)d_in[20];
    const float* bx_d1  = (const float*)d_in[21];
    const float* bh_d1  = (const float*)d_in[22];
    const float* W_out  = (const float*)d_in[23];
    const float* b_out  = (const float*)d_in[24];
    float* out = (float*)d_out;

    char* ws = (char*)d_ws;
    size_t off = 0;
    auto alloc = [&](size_t bytes) -> void* {
        void* p = ws + off; off += (bytes + 255) & ~(size_t)255; return p;
    };
    float* emb_e   = (float*)alloc((size_t)2048 * 256 * 4);
    float* gi_buf  = (float*)alloc((size_t)2048 * 1536 * 4);   // reused as pre_gid
    float* y0      = (float*)alloc((size_t)2048 * 512 * 4);
    float* enc_out = (float*)alloc((size_t)2048 * 512 * 4);
    float* pre_enc = (float*)alloc((size_t)2048 * 512 * 4);
    float* emb_d   = (float*)alloc((size_t)2048 * 256 * 4);
    float* H1      = (float*)alloc((size_t)2048 * 512 * 4);
    float* hA0 = (float*)alloc(32 * 512 * 4);
    float* hB0 = (float*)alloc(32 * 512 * 4);
    float* hA1 = (float*)alloc(32 * 512 * 4);
    float* hB1 = (float*)alloc(32 * 512 * 4);
    float* ctx = (float*)alloc(32 * 512 * 4);
    float* ph  = (float*)alloc(32 * 512 * 4);
    float* WhT_e0 = (float*)alloc((size_t)1536 * 512 * 4);
    float* WhT_e1 = (float*)alloc((size_t)1536 * 512 * 4);
    float* WhT_d0 = (float*)alloc((size_t)1536 * 512 * 4);
    float* WcT_d0 = (float*)alloc((size_t)1536 * 512 * 4);
    float* WxT_d1 = (float*)alloc((size_t)1536 * 512 * 4);
    float* WhT_d1 = (float*)alloc((size_t)1536 * 512 * 4);
    float* WaT    = (float*)alloc((size_t)512 * 512 * 4);

    // ---- one-time weight pack-transposes ----
    k_transpose4<<<dim3(16, 48), dim3(256), 0, stream>>>(Wh_e0, WhT_e0, 1536, 512, 0);
    k_transpose4<<<dim3(16, 48), dim3(256), 0, stream>>>(Wh_e1, WhT_e1, 1536, 512, 0);
    k_transpose4<<<dim3(16, 48), dim3(256), 0, stream>>>(Wh_d0, WhT_d0, 1536, 512, 0);
    k_transpose4<<<dim3(16, 48), dim3(256), 0, stream>>>(Wx_d0, WcT_d0, 1536, 768, 256);
    k_transpose4<<<dim3(16, 48), dim3(256), 0, stream>>>(Wx_d1, WxT_d1, 1536, 512, 0);
    k_transpose4<<<dim3(16, 48), dim3(256), 0, stream>>>(Wh_d1, WhT_d1, 1536, 512, 0);
    k_transpose4<<<dim3(16, 16), dim3(256), 0, stream>>>(W_attn, WaT, 512, 1024, 0);

    k_zero2<<<dim3(64), dim3(256), 0, stream>>>(hA0, hA1);

    // ---- encoder ----
    k_gather_enc<<<dim3(2048), dim3(64), 0, stream>>>(seq, E_enc, emb_e);
    k_sgemm<<<dim3(24, 32), dim3(256), 0, stream>>>(
        emb_e, 256, Wx_e0, 256, 0, bx_e0, gi_buf, 1536, 256, 0);
    {
        float *cur = hA0, *nxt = hB0;
        for (int s = 0; s < 64; s++) {
            k_gru_step<<<dim3(16, 4), dim3(256), 0, stream>>>(
                gi_buf + (size_t)s * 32 * 1536, WhT_e0, bh_e0, cur, nxt,
                y0 + (size_t)s * 32 * 512, 512);
            float* t = cur; cur = nxt; nxt = t;
        }
        // he0 ends in hA0
    }
    k_sgemm<<<dim3(24, 32), dim3(256), 0, stream>>>(
        y0, 512, Wx_e1, 512, 0, bx_e1, gi_buf, 1536, 512, 0);
    {
        float *cur = hA1, *nxt = hB1;
        for (int s = 0; s < 64; s++) {
            k_gru_step<<<dim3(16, 4), dim3(256), 0, stream>>>(
                gi_buf + (size_t)s * 32 * 1536, WhT_e1, bh_e1, cur, nxt,
                enc_out + (size_t)s * 512, 64 * 512);
            float* t = cur; cur = nxt; nxt = t;
        }
        // he1 in hA1
    }

    // ---- decoder precompute ----
    k_sgemm<<<dim3(8, 32), dim3(256), 0, stream>>>(
        enc_out, 512, W_attn, 1024, 512, b_attn, pre_enc, 512, 512, 0);
    k_gather_dec<<<dim3(2048), dim3(64), 0, stream>>>(tgt, E_dec, emb_d);
    float* pre_gid = gi_buf;   // encoder done with gi_buf; reuse
    k_sgemm<<<dim3(24, 32), dim3(256), 0, stream>>>(
        emb_d, 256, Wx_d0, 768, 0, bx_d0, pre_gid, 1536, 256, 0);

    // ---- decoder loop ----
    {
        float *c0 = hA0, *n0 = hB0, *c1 = hA1, *n1 = hB1;
        for (int t = 0; t < 64; t++) {
            k_attn_ph<<<dim3(16, 4), dim3(256), 0, stream>>>(c1, WaT, ph);
            k_attn_sc<<<dim3(32), dim3(256), 0, stream>>>(
                ph, pre_enc, enc_out, v_attn, ctx);
            k_gru_d0<<<dim3(16, 4), dim3(256), 0, stream>>>(
                pre_gid + (size_t)t * 32 * 1536, WhT_d0, WcT_d0, bh_d0, ctx, c0, n0);
            k_gru_d1<<<dim3(16, 4), dim3(256), 0, stream>>>(
                WxT_d1, bx_d1, WhT_d1, bh_d1, n0, c1, n1, H1 + (size_t)t * 32 * 512);
            float* tmp;
            tmp = c0; c0 = n0; n0 = tmp;
            tmp = c1; c1 = n1; n1 = tmp;
        }
    }

    // ---- logits = H1 @ W_out^T + b_out -> out[b,t,v] ----
    k_sgemm<<<dim3(500, 32), dim3(256), 0, stream>>>(
        H1, 512, W_out, 512, 0, b_out, out, 32000, 512, 1);

    (void)in_sizes; (void)n_in; (void)out_size; (void)ws_size;
}